// Round 1
// baseline (417.384 us; speedup 1.0000x reference)
//
#include <hip/hip_runtime.h>

typedef _Float16 half8 __attribute__((ext_vector_type(8)));
typedef float f32x4 __attribute__((ext_vector_type(4)));

#define SEQ   4096
#define DIN   512
#define HID   1024
#define KMEM  256
#define NB    8
#define KC    768        // KMEM + DIN
#define VP    4352       // padded length of each phase copy of reversed u
#define OUT_H_ELEMS 33554432ull   // 8*4096*1024

// ---------------- prep: cast H and W_h_w to fp16, zero v2 ----------------
__global__ __launch_bounds__(256) void prep_kernel(
    const float* __restrict__ Hf, const float* __restrict__ Wf,
    _Float16* __restrict__ Hh, _Float16* __restrict__ Wh,
    _Float16* __restrict__ v2)
{
  int tid = blockIdx.x * 256 + threadIdx.x;
  int stride = gridDim.x * 256;
  for (int i = tid; i < KMEM * SEQ; i += stride) Hh[i] = (_Float16)Hf[i];
  for (int i = tid; i < HID * KC;  i += stride) Wh[i] = (_Float16)Wf[i];
  for (int i = tid; i < NB * 8 * VP; i += stride) v2[i] = (_Float16)0.f;
}

// ---------------- u = relu(x . W_u + b); also emit x in fp16 and the
// reversed/zero-padded/8-phase-replicated u buffer v2 ----------------
// v2[b][p][t] = (0 <= t-p < 4096) ? u[b, 4095 - (t-p)] : 0
__global__ __launch_bounds__(256) void u_kernel(
    const float* __restrict__ x, const float* __restrict__ Wu,
    const float* __restrict__ Wub,
    _Float16* __restrict__ xh, _Float16* __restrict__ v2)
{
  int w = threadIdx.x >> 6, lane = threadIdx.x & 63;
  int row = blockIdx.x * 4 + w;               // 0..32767  (= b*4096 + s)
  const float4* xr = (const float4*)(x + (size_t)row * DIN);
  const float4* wr = (const float4*)Wu;
  float4 a0 = xr[lane * 2], a1 = xr[lane * 2 + 1];
  float4 w0 = wr[lane * 2], w1 = wr[lane * 2 + 1];
  float dot = a0.x * w0.x + a0.y * w0.y + a0.z * w0.z + a0.w * w0.w
            + a1.x * w1.x + a1.y * w1.y + a1.z * w1.z + a1.w * w1.w;
  // emit x in fp16 (coalesced 16B per lane)
  half8 hv;
  hv[0] = (_Float16)a0.x; hv[1] = (_Float16)a0.y;
  hv[2] = (_Float16)a0.z; hv[3] = (_Float16)a0.w;
  hv[4] = (_Float16)a1.x; hv[5] = (_Float16)a1.y;
  hv[6] = (_Float16)a1.z; hv[7] = (_Float16)a1.w;
  *((half8*)(xh + (size_t)row * DIN + lane * 8)) = hv;
  // wave reduction (64 lanes)
  #pragma unroll
  for (int off = 32; off > 0; off >>= 1) dot += __shfl_xor(dot, off);
  float u = dot + Wub[0];
  u = u > 0.f ? u : 0.f;
  if (lane < 8) {
    int s = row & (SEQ - 1), b = row >> 12;
    v2[(size_t)b * 8 * VP + (size_t)lane * VP + (4095 - s + lane)] = (_Float16)u;
  }
}

// ---------------- conv: m[b,s,k] = sum_{r=0..s} u[b,s-r] * H[k,r] ----------------
// Tile: 128 s-rows x 128 k-cols per block (4 waves, each 64x64 = 4x4 MFMA 16x16x32).
// B-operand (H) staged in LDS; A-operand (Toeplitz u) gathered per-lane from v2
// (phase-replicated so every 16B fragment load is aligned; pad zeros give the
// triangular mask for free).
__global__ __launch_bounds__(256) void conv_kernel(
    const _Float16* __restrict__ Hh, const _Float16* __restrict__ v2,
    _Float16* __restrict__ mh)
{
  __shared__ _Float16 Bs[128 * 40];       // [k-local][r-local], stride 40 halves
  int cb = blockIdx.x;                    // 0..15
  int b = cb >> 1, kt = cb & 1;
  int its = 31 - blockIdx.y;              // s-tile index, heavy tiles dispatched first
  int s0 = its * 128, k0 = kt * 128;
  int tid = threadIdx.x;
  int w = tid >> 6, lane = tid & 63;
  int wr = w >> 1, wc = w & 1;
  int lm = lane & 15, q = lane >> 4;
  const _Float16* v2b = v2 + (size_t)b * 8 * VP;

  int Eb[4];
  #pragma unroll
  for (int mi = 0; mi < 4; mi++)
    Eb[mi] = 4095 - (s0 + wr * 64 + mi * 16 + lm) + q * 8;

  f32x4 acc[4][4] = {};
  int iters = 4 * (its + 1);
  for (int it = 0; it < iters; ++it) {
    int r0 = it * 32;
    __syncthreads();
    #pragma unroll
    for (int p2 = 0; p2 < 2; p2++) {
      int u0 = p2 * 256 + tid;
      int rowB = u0 >> 2, ch = u0 & 3;
      half8 hvv = *((const half8*)(Hh + (size_t)(k0 + rowB) * SEQ + r0 + ch * 8));
      *((half8*)(Bs + rowB * 40 + ch * 8)) = hvv;
    }
    __syncthreads();
    half8 af[4], bf[4];
    #pragma unroll
    for (int mi = 0; mi < 4; mi++) {
      int E0 = Eb[mi] + r0;
      int p = (-E0) & 7;                          // (E0+p) % 8 == 0 -> 16B aligned
      af[mi] = *((const half8*)(v2b + (size_t)p * VP + E0 + p));
    }
    #pragma unroll
    for (int ni = 0; ni < 4; ni++) {
      int col = wc * 64 + ni * 16 + lm;
      bf[ni] = *((const half8*)(Bs + col * 40 + q * 8));
    }
    #pragma unroll
    for (int mi = 0; mi < 4; mi++)
      #pragma unroll
      for (int ni = 0; ni < 4; ni++)
        acc[mi][ni] = __builtin_amdgcn_mfma_f32_16x16x32_f16(af[mi], bf[ni], acc[mi][ni], 0, 0, 0);
  }
  // epilogue: write m in fp16 (input to the h-GEMM)
  size_t rowbase = (size_t)b * SEQ;
  #pragma unroll
  for (int mi = 0; mi < 4; mi++) {
    #pragma unroll
    for (int ni = 0; ni < 4; ni++) {
      int kout = k0 + wc * 64 + ni * 16 + lm;
      #pragma unroll
      for (int r = 0; r < 4; r++) {
        int sout = s0 + wr * 64 + mi * 16 + q * 4 + r;
        mh[(rowbase + sout) * KMEM + kout] = (_Float16)acc[mi][ni][r];
      }
    }
  }
}

// ---------------- h = relu([m, x] . W_h^T + b); also h[:, -1, :] tail ----------------
// GEMM M=32768 N=1024 K=768, 128x128 tile per block.
__global__ __launch_bounds__(256) void h_kernel(
    const _Float16* __restrict__ mh, const _Float16* __restrict__ xh,
    const _Float16* __restrict__ Wh, const float* __restrict__ Whb,
    float* __restrict__ out)
{
  __shared__ _Float16 As[128 * 40];
  __shared__ _Float16 Bs[128 * 40];
  int nt = blockIdx.x, mt = blockIdx.y;
  int tid = threadIdx.x, w = tid >> 6, lane = tid & 63;
  int wr = w >> 1, wc = w & 1, lm = lane & 15, q = lane >> 4;

  f32x4 acc[4][4] = {};
  for (int it = 0; it < 24; ++it) {
    int kk = it * 32;
    __syncthreads();
    #pragma unroll
    for (int p2 = 0; p2 < 2; p2++) {
      int u0 = p2 * 256 + tid;
      int row = u0 >> 2, ch = u0 & 3;
      size_t rg = (size_t)mt * 128 + row;
      const _Float16* srcA = (kk < KMEM)
          ? (mh + rg * KMEM + kk + ch * 8)
          : (xh + rg * DIN + (kk - KMEM) + ch * 8);
      *((half8*)(As + row * 40 + ch * 8)) = *((const half8*)srcA);
      const _Float16* srcB = Wh + (size_t)(nt * 128 + row) * KC + kk + ch * 8;
      *((half8*)(Bs + row * 40 + ch * 8)) = *((const half8*)srcB);
    }
    __syncthreads();
    half8 af[4], bf[4];
    #pragma unroll
    for (int mi = 0; mi < 4; mi++)
      af[mi] = *((const half8*)(As + (wr * 64 + mi * 16 + lm) * 40 + q * 8));
    #pragma unroll
    for (int ni = 0; ni < 4; ni++)
      bf[ni] = *((const half8*)(Bs + (wc * 64 + ni * 16 + lm) * 40 + q * 8));
    #pragma unroll
    for (int mi = 0; mi < 4; mi++)
      #pragma unroll
      for (int ni = 0; ni < 4; ni++)
        acc[mi][ni] = __builtin_amdgcn_mfma_f32_16x16x32_f16(af[mi], bf[ni], acc[mi][ni], 0, 0, 0);
  }
  // epilogue: bias + relu + store fp32 (+ last-timestep tail)
  #pragma unroll
  for (int ni = 0; ni < 4; ni++) {
    int colg = nt * 128 + wc * 64 + ni * 16 + lm;
    float bias = Whb[colg];
    #pragma unroll
    for (int mi = 0; mi < 4; mi++) {
      #pragma unroll
      for (int r = 0; r < 4; r++) {
        int rowg = mt * 128 + wr * 64 + mi * 16 + q * 4 + r;
        float v = acc[mi][ni][r] + bias;
        v = v > 0.f ? v : 0.f;
        out[(size_t)rowg * HID + colg] = v;
        if ((rowg & (SEQ - 1)) == SEQ - 1)
          out[OUT_H_ELEMS + (size_t)(rowg >> 12) * HID + colg] = v;
      }
    }
  }
}

extern "C" void kernel_launch(void* const* d_in, const int* in_sizes, int n_in,
                              void* d_out, int out_size, void* d_ws, size_t ws_size,
                              hipStream_t stream) {
  const float* x   = (const float*)d_in[0];   // (8, 4096, 512)
  const float* Wu  = (const float*)d_in[1];   // (1, 512)
  const float* Wub = (const float*)d_in[2];   // (1,)
  const float* Whw = (const float*)d_in[3];   // (1024, 768)
  const float* Whb = (const float*)d_in[4];   // (1024,)
  const float* Hf  = (const float*)d_in[5];   // (256, 4096)
  float* out = (float*)d_out;

  char* ws = (char*)d_ws;
  _Float16* Hh = (_Float16*)(ws);                         // 2,097,152 B
  _Float16* Wh = (_Float16*)(ws + 2097152);               // 1,572,864 B
  _Float16* v2 = (_Float16*)(ws + 3670016);               //   557,056 B
  _Float16* xh = (_Float16*)(ws + 4227072);               // 33,554,432 B
  _Float16* mh = (_Float16*)(ws + 37781504);              // 16,777,216 B  (end 54,558,720)

  prep_kernel<<<dim3(1024), dim3(256), 0, stream>>>(Hf, Whw, Hh, Wh, v2);
  u_kernel<<<dim3(8192), dim3(256), 0, stream>>>(x, Wu, Wub, xh, v2);
  conv_kernel<<<dim3(16, 32), dim3(256), 0, stream>>>(Hh, v2, mh);
  h_kernel<<<dim3(8, 256), dim3(256), 0, stream>>>(mh, xh, Wh, Whb, out);
}

// Round 2
// 413.115 us; speedup vs baseline: 1.0103x; 1.0103x over previous
//
#include <hip/hip_runtime.h>

typedef _Float16 half8 __attribute__((ext_vector_type(8)));
typedef float f32x4 __attribute__((ext_vector_type(4)));

#define SEQ   4096
#define DIN   512
#define HID   1024
#define KMEM  256
#define NB    8
#define KC    768        // KMEM + DIN
#define VP    4352       // padded length of each phase copy of reversed u
#define OUT_H_ELEMS 33554432ull   // 8*4096*1024

__device__ __forceinline__ void load_lds16(const void* g, void* l) {
  __builtin_amdgcn_global_load_lds(
      (const __attribute__((address_space(1))) unsigned int*)g,
      (__attribute__((address_space(3))) unsigned int*)l, 16, 0, 0);
}

// ---------------- prep: cast H and W_h_w to fp16, zero v2 ----------------
__global__ __launch_bounds__(256) void prep_kernel(
    const float* __restrict__ Hf, const float* __restrict__ Wf,
    _Float16* __restrict__ Hh, _Float16* __restrict__ Wh,
    _Float16* __restrict__ v2)
{
  int tid = blockIdx.x * 256 + threadIdx.x;
  int stride = gridDim.x * 256;
  for (int i = tid; i < KMEM * SEQ; i += stride) Hh[i] = (_Float16)Hf[i];
  for (int i = tid; i < HID * KC;  i += stride) Wh[i] = (_Float16)Wf[i];
  for (int i = tid; i < NB * 8 * VP; i += stride) v2[i] = (_Float16)0.f;
}

// ---------------- u = relu(x . W_u + b); emit xh (fp16) and v2 ----------------
// v2[b][p][t] = (0 <= t-p < 4096) ? u[b, 4095 - (t-p)] : 0
__global__ __launch_bounds__(256) void u_kernel(
    const float* __restrict__ x, const float* __restrict__ Wu,
    const float* __restrict__ Wub,
    _Float16* __restrict__ xh, _Float16* __restrict__ v2)
{
  int w = threadIdx.x >> 6, lane = threadIdx.x & 63;
  int row = blockIdx.x * 4 + w;               // 0..32767  (= b*4096 + s)
  const float4* xr = (const float4*)(x + (size_t)row * DIN);
  const float4* wr = (const float4*)Wu;
  float4 a0 = xr[lane * 2], a1 = xr[lane * 2 + 1];
  float4 w0 = wr[lane * 2], w1 = wr[lane * 2 + 1];
  float dot = a0.x * w0.x + a0.y * w0.y + a0.z * w0.z + a0.w * w0.w
            + a1.x * w1.x + a1.y * w1.y + a1.z * w1.z + a1.w * w1.w;
  half8 hv;
  hv[0] = (_Float16)a0.x; hv[1] = (_Float16)a0.y;
  hv[2] = (_Float16)a0.z; hv[3] = (_Float16)a0.w;
  hv[4] = (_Float16)a1.x; hv[5] = (_Float16)a1.y;
  hv[6] = (_Float16)a1.z; hv[7] = (_Float16)a1.w;
  *((half8*)(xh + (size_t)row * DIN + lane * 8)) = hv;
  #pragma unroll
  for (int off = 32; off > 0; off >>= 1) dot += __shfl_xor(dot, off);
  float u = dot + Wub[0];
  u = u > 0.f ? u : 0.f;
  if (lane < 8) {
    int s = row & (SEQ - 1), b = row >> 12;
    v2[(size_t)b * 8 * VP + (size_t)lane * VP + (4095 - s + lane)] = (_Float16)u;
  }
}

// ---------------- conv: m[b,s,k] = sum_{r=0..s} u[b,s-r] * H[k,r] ----------------
// No LDS, no barriers: A (Toeplitz u) and B (H rows) fragments both gathered
// directly from global (L2-resident: v2=557KB, H=2MB). Register double-buffer,
// manual unroll-by-2 prefetch => 8 loads in flight per wave, branch-free.
// Snake s-tile order: paired blocks (j, j+256) sum to constant 132 iters.
__global__ __launch_bounds__(256) void conv_kernel(
    const _Float16* __restrict__ Hh, const _Float16* __restrict__ v2,
    _Float16* __restrict__ mh)
{
  int cb = blockIdx.x;                    // 0..15
  int b = cb >> 1, kt = cb & 1;
  int by = blockIdx.y;
  int its = (by < 16) ? (31 - by) : (by - 16);   // snake: heavy half then light half
  int s0 = its * 128, k0 = kt * 128;
  int tid = threadIdx.x;
  int w = tid >> 6, lane = tid & 63;
  int wr = w >> 1, wc = w & 1;
  int lm = lane & 15, q = lane >> 4;
  const _Float16* v2b = v2 + (size_t)b * 8 * VP;

  const _Float16* aptr[4];
  const _Float16* bptr[4];
  #pragma unroll
  for (int mi = 0; mi < 4; mi++) {
    int E0 = 4095 - (s0 + wr * 64 + mi * 16 + lm) + q * 8;
    int p = (-E0) & 7;                    // constant across iters (step 32 % 8 == 0)
    aptr[mi] = v2b + (size_t)p * VP + E0 + p;
  }
  #pragma unroll
  for (int ni = 0; ni < 4; ni++) {
    int col = k0 + wc * 64 + ni * 16 + lm;
    bptr[ni] = Hh + (size_t)col * SEQ + q * 8;
  }

  f32x4 acc[4][4] = {};
  half8 A0[4], B0[4], A1[4], B1[4];
  #pragma unroll
  for (int mi = 0; mi < 4; mi++) A0[mi] = *((const half8*)(aptr[mi]));
  #pragma unroll
  for (int ni = 0; ni < 4; ni++) B0[ni] = *((const half8*)(bptr[ni]));

  int iters = 4 * (its + 1);              // always even
  for (int it = 0; it < iters; it += 2) {
    int r1 = (it + 1) * 32, r2 = (it + 2) * 32;
    #pragma unroll
    for (int mi = 0; mi < 4; mi++) A1[mi] = *((const half8*)(aptr[mi] + r1));
    #pragma unroll
    for (int ni = 0; ni < 4; ni++) B1[ni] = *((const half8*)(bptr[ni] + r1));
    #pragma unroll
    for (int mi = 0; mi < 4; mi++)
      #pragma unroll
      for (int ni = 0; ni < 4; ni++)
        acc[mi][ni] = __builtin_amdgcn_mfma_f32_16x16x32_f16(A0[mi], B0[ni], acc[mi][ni], 0, 0, 0);
    #pragma unroll
    for (int mi = 0; mi < 4; mi++) A0[mi] = *((const half8*)(aptr[mi] + r2));
    #pragma unroll
    for (int ni = 0; ni < 4; ni++) B0[ni] = *((const half8*)(bptr[ni] + r2));
    #pragma unroll
    for (int mi = 0; mi < 4; mi++)
      #pragma unroll
      for (int ni = 0; ni < 4; ni++)
        acc[mi][ni] = __builtin_amdgcn_mfma_f32_16x16x32_f16(A1[mi], B1[ni], acc[mi][ni], 0, 0, 0);
  }
  // epilogue: write m in fp16 (input to the h-GEMM)
  size_t rowbase = (size_t)b * SEQ;
  #pragma unroll
  for (int mi = 0; mi < 4; mi++) {
    #pragma unroll
    for (int ni = 0; ni < 4; ni++) {
      int kout = k0 + wc * 64 + ni * 16 + lm;
      #pragma unroll
      for (int r = 0; r < 4; r++) {
        int sout = s0 + wr * 64 + mi * 16 + q * 4 + r;
        mh[(rowbase + sout) * KMEM + kout] = (_Float16)acc[mi][ni][r];
      }
    }
  }
}

// ---------------- h = relu([m, x] . W_h^T + b); also h[:, -1, :] tail ----------------
// GEMM M=32768 N=1024 K=768, 128x128 tile, m97 structure:
// global_load_lds width-16 staging into unpadded [128][32] LDS.
__global__ __launch_bounds__(256) void h_kernel(
    const _Float16* __restrict__ mh, const _Float16* __restrict__ xh,
    const _Float16* __restrict__ Wh, const float* __restrict__ Whb,
    float* __restrict__ out)
{
  __shared__ _Float16 As[128 * 32];
  __shared__ _Float16 Bs[128 * 32];
  int nt = blockIdx.x, mt = blockIdx.y;
  int tid = threadIdx.x, w = tid >> 6, lane = tid & 63;
  int wr = w >> 1, wc = w & 1, lm = lane & 15, q = lane >> 4;

  f32x4 acc[4][4] = {};
  for (int it = 0; it < 24; ++it) {
    int kk = it * 32;
    __syncthreads();
    #pragma unroll
    for (int p2 = 0; p2 < 2; p2++) {
      int c = p2 * 256 + tid;             // chunk id; dst = wave-uniform + lane*16
      int row = c >> 2, ch = c & 3;
      size_t rg = (size_t)mt * 128 + row;
      const _Float16* srcA = (kk < KMEM)
          ? (mh + rg * KMEM + kk + ch * 8)
          : (xh + rg * DIN + (kk - KMEM) + ch * 8);
      load_lds16(srcA, As + (size_t)c * 8);
      const _Float16* srcB = Wh + (size_t)(nt * 128 + row) * KC + kk + ch * 8;
      load_lds16(srcB, Bs + (size_t)c * 8);
    }
    __syncthreads();
    half8 af[4], bf[4];
    #pragma unroll
    for (int mi = 0; mi < 4; mi++)
      af[mi] = *((const half8*)(As + (wr * 64 + mi * 16 + lm) * 32 + q * 8));
    #pragma unroll
    for (int ni = 0; ni < 4; ni++)
      bf[ni] = *((const half8*)(Bs + (wc * 64 + ni * 16 + lm) * 32 + q * 8));
    #pragma unroll
    for (int mi = 0; mi < 4; mi++)
      #pragma unroll
      for (int ni = 0; ni < 4; ni++)
        acc[mi][ni] = __builtin_amdgcn_mfma_f32_16x16x32_f16(af[mi], bf[ni], acc[mi][ni], 0, 0, 0);
  }
  // epilogue: bias + relu + store fp32 (+ last-timestep tail)
  #pragma unroll
  for (int ni = 0; ni < 4; ni++) {
    int colg = nt * 128 + wc * 64 + ni * 16 + lm;
    float bias = Whb[colg];
    #pragma unroll
    for (int mi = 0; mi < 4; mi++) {
      #pragma unroll
      for (int r = 0; r < 4; r++) {
        int rowg = mt * 128 + wr * 64 + mi * 16 + q * 4 + r;
        float v = acc[mi][ni][r] + bias;
        v = v > 0.f ? v : 0.f;
        out[(size_t)rowg * HID + colg] = v;
        if ((rowg & (SEQ - 1)) == SEQ - 1)
          out[OUT_H_ELEMS + (size_t)(rowg >> 12) * HID + colg] = v;
      }
    }
  }
}

extern "C" void kernel_launch(void* const* d_in, const int* in_sizes, int n_in,
                              void* d_out, int out_size, void* d_ws, size_t ws_size,
                              hipStream_t stream) {
  const float* x   = (const float*)d_in[0];   // (8, 4096, 512)
  const float* Wu  = (const float*)d_in[1];   // (1, 512)
  const float* Wub = (const float*)d_in[2];   // (1,)
  const float* Whw = (const float*)d_in[3];   // (1024, 768)
  const float* Whb = (const float*)d_in[4];   // (1024,)
  const float* Hf  = (const float*)d_in[5];   // (256, 4096)
  float* out = (float*)d_out;

  char* ws = (char*)d_ws;
  _Float16* Hh = (_Float16*)(ws);                         // 2,097,152 B
  _Float16* Wh = (_Float16*)(ws + 2097152);               // 1,572,864 B
  _Float16* v2 = (_Float16*)(ws + 3670016);               //   557,056 B
  _Float16* xh = (_Float16*)(ws + 4227072);               // 33,554,432 B
  _Float16* mh = (_Float16*)(ws + 37781504);              // 16,777,216 B  (end 54,558,720)

  prep_kernel<<<dim3(1024), dim3(256), 0, stream>>>(Hf, Whw, Hh, Wh, v2);
  u_kernel<<<dim3(8192), dim3(256), 0, stream>>>(x, Wu, Wub, xh, v2);
  conv_kernel<<<dim3(16, 32), dim3(256), 0, stream>>>(Hh, v2, mh);
  h_kernel<<<dim3(8, 256), dim3(256), 0, stream>>>(mh, xh, Wh, Whb, out);
}

// Round 3
// 373.165 us; speedup vs baseline: 1.1185x; 1.1071x over previous
//
#include <hip/hip_runtime.h>

typedef _Float16 half8 __attribute__((ext_vector_type(8)));
typedef float f32x4 __attribute__((ext_vector_type(4)));

#define SEQ   4096
#define DIN   512
#define HID   1024
#define KMEM  256
#define NB    8
#define KC    768        // KMEM + DIN
#define VP    4352       // padded length of each phase copy of reversed u
#define OUT_H_ELEMS 33554432ull   // 8*4096*1024

__device__ __forceinline__ void load_lds16(const void* g, void* l) {
  __builtin_amdgcn_global_load_lds(
      (const __attribute__((address_space(1))) unsigned int*)g,
      (__attribute__((address_space(3))) unsigned int*)l, 16, 0, 0);
}

// ---------------- prep: cast H and W_h_w to fp16, zero v2 ----------------
__global__ __launch_bounds__(256) void prep_kernel(
    const float* __restrict__ Hf, const float* __restrict__ Wf,
    _Float16* __restrict__ Hh, _Float16* __restrict__ Wh,
    _Float16* __restrict__ v2)
{
  int tid = blockIdx.x * 256 + threadIdx.x;
  int stride = gridDim.x * 256;
  for (int i = tid; i < KMEM * SEQ; i += stride) Hh[i] = (_Float16)Hf[i];
  for (int i = tid; i < HID * KC;  i += stride) Wh[i] = (_Float16)Wf[i];
  for (int i = tid; i < NB * 8 * VP; i += stride) v2[i] = (_Float16)0.f;
}

// ---------------- u = relu(x . W_u + b); emit xh (fp16) and v2 ----------------
// v2[b][p][t] = (0 <= t-p < 4096) ? u[b, 4095 - (t-p)] : 0
__global__ __launch_bounds__(256) void u_kernel(
    const float* __restrict__ x, const float* __restrict__ Wu,
    const float* __restrict__ Wub,
    _Float16* __restrict__ xh, _Float16* __restrict__ v2)
{
  int w = threadIdx.x >> 6, lane = threadIdx.x & 63;
  int row = blockIdx.x * 4 + w;               // 0..32767  (= b*4096 + s)
  const float4* xr = (const float4*)(x + (size_t)row * DIN);
  const float4* wr = (const float4*)Wu;
  float4 a0 = xr[lane * 2], a1 = xr[lane * 2 + 1];
  float4 w0 = wr[lane * 2], w1 = wr[lane * 2 + 1];
  float dot = a0.x * w0.x + a0.y * w0.y + a0.z * w0.z + a0.w * w0.w
            + a1.x * w1.x + a1.y * w1.y + a1.z * w1.z + a1.w * w1.w;
  half8 hv;
  hv[0] = (_Float16)a0.x; hv[1] = (_Float16)a0.y;
  hv[2] = (_Float16)a0.z; hv[3] = (_Float16)a0.w;
  hv[4] = (_Float16)a1.x; hv[5] = (_Float16)a1.y;
  hv[6] = (_Float16)a1.z; hv[7] = (_Float16)a1.w;
  *((half8*)(xh + (size_t)row * DIN + lane * 8)) = hv;
  #pragma unroll
  for (int off = 32; off > 0; off >>= 1) dot += __shfl_xor(dot, off);
  float u = dot + Wub[0];
  u = u > 0.f ? u : 0.f;
  if (lane < 8) {
    int s = row & (SEQ - 1), b = row >> 12;
    v2[(size_t)b * 8 * VP + (size_t)lane * VP + (4095 - s + lane)] = (_Float16)u;
  }
}

// ---------------- conv: m[b,s,k] = sum_{r=0..s} u[b,s-r] * H[k,r] ----------------
// m97 structure: BOTH operands staged coalesced via global_load_lds width-16.
// B = H tile [128 cols][32 r] (8 KB). A = the 160-element reversed-u window,
// 8-phase-replicated (8 x 336 B) so every ds_read_b128 is 16B-aligned; pad
// zeros in v2 implement the triangular mask. A-frag LDS offsets are
// loop-invariant (the window slides in global, its LDS image doesn't).
__global__ __launch_bounds__(256) void conv_kernel(
    const _Float16* __restrict__ Hh, const _Float16* __restrict__ v2,
    _Float16* __restrict__ mh)
{
  __shared__ _Float16 Bs[128 * 32];   // [col][r-chunk], stride 32 (bank-optimal)
  __shared__ _Float16 Aw[8 * 168];    // 8 phase copies of the window
  int cb = blockIdx.x;                // 0..15
  int b = cb >> 1, kt = cb & 1;
  int by = blockIdx.y;
  int its = (by < 16) ? (31 - by) : (by - 16);   // snake: heavy half then light
  int s0 = its * 128, k0 = kt * 128;
  int tid = threadIdx.x;
  int w = tid >> 6, lane = tid & 63;
  int wr = w >> 1, wc = w & 1;
  int lm = lane & 15, q = lane >> 4;
  const _Float16* v2b = v2 + (size_t)b * 8 * VP;
  int gbase0 = 3968 - s0;             // window start at r0=0 (8-aligned, >=0)

  // loop-invariant A-frag LDS pointers
  const _Float16* aoff[4];
  #pragma unroll
  for (int mi = 0; mi < 4; mi++) {
    int X = wr * 64 + mi * 16 + lm;   // s-offset within tile
    int p = (X + 1) & 7;              // phase making the read 16B-aligned
    aoff[mi] = Aw + p * 168 + (127 - X + p) + q * 8;
  }
  // loop-invariant B-frag LDS pointers
  const _Float16* boff[4];
  #pragma unroll
  for (int ni = 0; ni < 4; ni++)
    boff[ni] = Bs + (wc * 64 + ni * 16 + lm) * 32 + q * 8;

  // A-staging thread mapping (168 chunks of 16B)
  int ap = tid / 21, aidx = tid - ap * 21;

  f32x4 acc[4][4] = {};
  int iters = 4 * (its + 1);
  for (int it = 0; it < iters; ++it) {
    int r0 = it * 32;
    __syncthreads();
    if (tid < 168)
      load_lds16(v2b + (size_t)ap * VP + gbase0 + r0 + aidx * 8, Aw + tid * 8);
    #pragma unroll
    for (int p2 = 0; p2 < 2; p2++) {
      int c = p2 * 256 + tid;
      int col = c >> 2, ch = c & 3;
      load_lds16(Hh + (size_t)(k0 + col) * SEQ + r0 + ch * 8, Bs + (size_t)c * 8);
    }
    __syncthreads();
    half8 af[4], bf[4];
    #pragma unroll
    for (int mi = 0; mi < 4; mi++) af[mi] = *((const half8*)(aoff[mi]));
    #pragma unroll
    for (int ni = 0; ni < 4; ni++) bf[ni] = *((const half8*)(boff[ni]));
    #pragma unroll
    for (int mi = 0; mi < 4; mi++)
      #pragma unroll
      for (int ni = 0; ni < 4; ni++)
        acc[mi][ni] = __builtin_amdgcn_mfma_f32_16x16x32_f16(af[mi], bf[ni], acc[mi][ni], 0, 0, 0);
  }
  // epilogue: write m in fp16 (input to the h-GEMM)
  size_t rowbase = (size_t)b * SEQ;
  #pragma unroll
  for (int mi = 0; mi < 4; mi++) {
    #pragma unroll
    for (int ni = 0; ni < 4; ni++) {
      int kout = k0 + wc * 64 + ni * 16 + lm;
      #pragma unroll
      for (int r = 0; r < 4; r++) {
        int sout = s0 + wr * 64 + mi * 16 + q * 4 + r;
        mh[(rowbase + sout) * KMEM + kout] = (_Float16)acc[mi][ni][r];
      }
    }
  }
}

// ---------------- h = relu([m, x] . W_h^T + b); also h[:, -1, :] tail ----------------
// GEMM M=32768 N=1024 K=768, 128x128 tile, m97 structure.
__global__ __launch_bounds__(256) void h_kernel(
    const _Float16* __restrict__ mh, const _Float16* __restrict__ xh,
    const _Float16* __restrict__ Wh, const float* __restrict__ Whb,
    float* __restrict__ out)
{
  __shared__ _Float16 As[128 * 32];
  __shared__ _Float16 Bs[128 * 32];
  int nt = blockIdx.x, mt = blockIdx.y;
  int tid = threadIdx.x, w = tid >> 6, lane = tid & 63;
  int wr = w >> 1, wc = w & 1, lm = lane & 15, q = lane >> 4;

  f32x4 acc[4][4] = {};
  for (int it = 0; it < 24; ++it) {
    int kk = it * 32;
    __syncthreads();
    #pragma unroll
    for (int p2 = 0; p2 < 2; p2++) {
      int c = p2 * 256 + tid;
      int row = c >> 2, ch = c & 3;
      size_t rg = (size_t)mt * 128 + row;
      const _Float16* srcA = (kk < KMEM)
          ? (mh + rg * KMEM + kk + ch * 8)
          : (xh + rg * DIN + (kk - KMEM) + ch * 8);
      load_lds16(srcA, As + (size_t)c * 8);
      const _Float16* srcB = Wh + (size_t)(nt * 128 + row) * KC + kk + ch * 8;
      load_lds16(srcB, Bs + (size_t)c * 8);
    }
    __syncthreads();
    half8 af[4], bf[4];
    #pragma unroll
    for (int mi = 0; mi < 4; mi++)
      af[mi] = *((const half8*)(As + (wr * 64 + mi * 16 + lm) * 32 + q * 8));
    #pragma unroll
    for (int ni = 0; ni < 4; ni++)
      bf[ni] = *((const half8*)(Bs + (wc * 64 + ni * 16 + lm) * 32 + q * 8));
    #pragma unroll
    for (int mi = 0; mi < 4; mi++)
      #pragma unroll
      for (int ni = 0; ni < 4; ni++)
        acc[mi][ni] = __builtin_amdgcn_mfma_f32_16x16x32_f16(af[mi], bf[ni], acc[mi][ni], 0, 0, 0);
  }
  // epilogue: bias + relu + store fp32 (+ last-timestep tail)
  #pragma unroll
  for (int ni = 0; ni < 4; ni++) {
    int colg = nt * 128 + wc * 64 + ni * 16 + lm;
    float bias = Whb[colg];
    #pragma unroll
    for (int mi = 0; mi < 4; mi++) {
      #pragma unroll
      for (int r = 0; r < 4; r++) {
        int rowg = mt * 128 + wr * 64 + mi * 16 + q * 4 + r;
        float v = acc[mi][ni][r] + bias;
        v = v > 0.f ? v : 0.f;
        out[(size_t)rowg * HID + colg] = v;
        if ((rowg & (SEQ - 1)) == SEQ - 1)
          out[OUT_H_ELEMS + (size_t)(rowg >> 12) * HID + colg] = v;
      }
    }
  }
}

extern "C" void kernel_launch(void* const* d_in, const int* in_sizes, int n_in,
                              void* d_out, int out_size, void* d_ws, size_t ws_size,
                              hipStream_t stream) {
  const float* x   = (const float*)d_in[0];   // (8, 4096, 512)
  const float* Wu  = (const float*)d_in[1];   // (1, 512)
  const float* Wub = (const float*)d_in[2];   // (1,)
  const float* Whw = (const float*)d_in[3];   // (1024, 768)
  const float* Whb = (const float*)d_in[4];   // (1024,)
  const float* Hf  = (const float*)d_in[5];   // (256, 4096)
  float* out = (float*)d_out;

  char* ws = (char*)d_ws;
  _Float16* Hh = (_Float16*)(ws);                         // 2,097,152 B
  _Float16* Wh = (_Float16*)(ws + 2097152);               // 1,572,864 B
  _Float16* v2 = (_Float16*)(ws + 3670016);               //   557,056 B
  _Float16* xh = (_Float16*)(ws + 4227072);               // 33,554,432 B
  _Float16* mh = (_Float16*)(ws + 37781504);              // 16,777,216 B  (end 54,558,720)

  prep_kernel<<<dim3(1024), dim3(256), 0, stream>>>(Hf, Whw, Hh, Wh, v2);
  u_kernel<<<dim3(8192), dim3(256), 0, stream>>>(x, Wu, Wub, xh, v2);
  conv_kernel<<<dim3(16, 32), dim3(256), 0, stream>>>(Hh, v2, mh);
  h_kernel<<<dim3(8, 256), dim3(256), 0, stream>>>(mh, xh, Wh, Whb, out);
}

// Round 4
// 345.409 us; speedup vs baseline: 1.2084x; 1.0804x over previous
//
#include <hip/hip_runtime.h>

typedef _Float16 half8 __attribute__((ext_vector_type(8)));
typedef float f32x4 __attribute__((ext_vector_type(4)));

#define SEQ   4096
#define DIN   512
#define HID   1024
#define KMEM  256
#define NB    8
#define KC    768        // KMEM + DIN
#define VP    4352       // padded length of each phase copy of reversed u
#define OUT_H_ELEMS 33554432ull   // 8*4096*1024

__device__ __forceinline__ void load_lds16(const void* g, void* l) {
  __builtin_amdgcn_global_load_lds(
      (const __attribute__((address_space(1))) unsigned int*)g,
      (__attribute__((address_space(3))) unsigned int*)l, 16, 0, 0);
}

// ---------------- prep: cast H and W_h_w to fp16, zero v2 ----------------
__global__ __launch_bounds__(256) void prep_kernel(
    const float* __restrict__ Hf, const float* __restrict__ Wf,
    _Float16* __restrict__ Hh, _Float16* __restrict__ Wh,
    _Float16* __restrict__ v2)
{
  int tid = blockIdx.x * 256 + threadIdx.x;
  int stride = gridDim.x * 256;
  for (int i = tid; i < KMEM * SEQ; i += stride) Hh[i] = (_Float16)Hf[i];
  for (int i = tid; i < HID * KC;  i += stride) Wh[i] = (_Float16)Wf[i];
  for (int i = tid; i < NB * 8 * VP; i += stride) v2[i] = (_Float16)0.f;
}

// ---------------- u = relu(x . W_u + b); emit xh (fp16) and v2 ----------------
// v2[b][p][t] = (0 <= t-p < 4096) ? u[b, 4095 - (t-p)] : 0
__global__ __launch_bounds__(256) void u_kernel(
    const float* __restrict__ x, const float* __restrict__ Wu,
    const float* __restrict__ Wub,
    _Float16* __restrict__ xh, _Float16* __restrict__ v2)
{
  int w = threadIdx.x >> 6, lane = threadIdx.x & 63;
  int row = blockIdx.x * 4 + w;               // 0..32767  (= b*4096 + s)
  const float4* xr = (const float4*)(x + (size_t)row * DIN);
  const float4* wr = (const float4*)Wu;
  float4 a0 = xr[lane * 2], a1 = xr[lane * 2 + 1];
  float4 w0 = wr[lane * 2], w1 = wr[lane * 2 + 1];
  float dot = a0.x * w0.x + a0.y * w0.y + a0.z * w0.z + a0.w * w0.w
            + a1.x * w1.x + a1.y * w1.y + a1.z * w1.z + a1.w * w1.w;
  half8 hv;
  hv[0] = (_Float16)a0.x; hv[1] = (_Float16)a0.y;
  hv[2] = (_Float16)a0.z; hv[3] = (_Float16)a0.w;
  hv[4] = (_Float16)a1.x; hv[5] = (_Float16)a1.y;
  hv[6] = (_Float16)a1.z; hv[7] = (_Float16)a1.w;
  *((half8*)(xh + (size_t)row * DIN + lane * 8)) = hv;
  #pragma unroll
  for (int off = 32; off > 0; off >>= 1) dot += __shfl_xor(dot, off);
  float u = dot + Wub[0];
  u = u > 0.f ? u : 0.f;
  if (lane < 8) {
    int s = row & (SEQ - 1), b = row >> 12;
    v2[(size_t)b * 8 * VP + (size_t)lane * VP + (4095 - s + lane)] = (_Float16)u;
  }
}

// ---------------- conv: m[b,s,k] = sum_{r=0..s} u[b,s-r] * H[k,r] ----------------
// Double-buffered global_load_lds staging, ONE barrier per iter: prefetch k+1
// into the alternate buffer right after the barrier, so the auto vmcnt(0)
// drain at the NEXT barrier waits on loads issued a full MFMA phase earlier.
__global__ __launch_bounds__(256) void conv_kernel(
    const _Float16* __restrict__ Hh, const _Float16* __restrict__ v2,
    _Float16* __restrict__ mh)
{
  __shared__ _Float16 Bs[2][128 * 32];  // [col][r-chunk], stride 32
  __shared__ _Float16 Aw[2][8 * 168];   // 8 phase copies of the u-window
  int cb = blockIdx.x;                  // 0..15
  int b = cb >> 1, kt = cb & 1;
  int by = blockIdx.y;
  int its = (by < 16) ? (31 - by) : (by - 16);   // snake: heavy half then light
  int s0 = its * 128, k0 = kt * 128;
  int tid = threadIdx.x;
  int w = tid >> 6, lane = tid & 63;
  int wr = w >> 1, wc = w & 1;
  int lm = lane & 15, q = lane >> 4;
  const _Float16* v2b = v2 + (size_t)b * 8 * VP;
  int gbase0 = 3968 - s0;               // window start at r0=0 (8-aligned, >=0)

  // loop-invariant A-frag LDS offsets (the window slides in global only)
  int aoffs[4];
  #pragma unroll
  for (int mi = 0; mi < 4; mi++) {
    int X = wr * 64 + mi * 16 + lm;
    int p = (X + 1) & 7;
    aoffs[mi] = p * 168 + (127 - X + p) + q * 8;
  }
  int boffs[4];
  #pragma unroll
  for (int ni = 0; ni < 4; ni++)
    boffs[ni] = (wc * 64 + ni * 16 + lm) * 32 + q * 8;

  int ap = tid / 21, aidx = tid - ap * 21;   // A-staging map (168 x 16B chunks)

  f32x4 acc[4][4] = {};
  int iters = 4 * (its + 1);

  // preload iter 0 into buf 0
  {
    if (tid < 168)
      load_lds16(v2b + (size_t)ap * VP + gbase0 + aidx * 8, Aw[0] + tid * 8);
    #pragma unroll
    for (int p2 = 0; p2 < 2; p2++) {
      int c = p2 * 256 + tid;
      int col = c >> 2, ch = c & 3;
      load_lds16(Hh + (size_t)(k0 + col) * SEQ + ch * 8, Bs[0] + (size_t)c * 8);
    }
  }

  for (int it = 0; it < iters; ++it) {
    int buf = it & 1;
    __syncthreads();                    // vmcnt(0): buf's loads landed; prev reads done
    if (it + 1 < iters) {               // prefetch next chunk into buf^1
      int r0 = (it + 1) * 32;
      if (tid < 168)
        load_lds16(v2b + (size_t)ap * VP + gbase0 + r0 + aidx * 8, Aw[buf ^ 1] + tid * 8);
      #pragma unroll
      for (int p2 = 0; p2 < 2; p2++) {
        int c = p2 * 256 + tid;
        int col = c >> 2, ch = c & 3;
        load_lds16(Hh + (size_t)(k0 + col) * SEQ + r0 + ch * 8, Bs[buf ^ 1] + (size_t)c * 8);
      }
    }
    half8 af[4], bf[4];
    #pragma unroll
    for (int mi = 0; mi < 4; mi++) af[mi] = *((const half8*)(Aw[buf] + aoffs[mi]));
    #pragma unroll
    for (int ni = 0; ni < 4; ni++) bf[ni] = *((const half8*)(Bs[buf] + boffs[ni]));
    #pragma unroll
    for (int mi = 0; mi < 4; mi++)
      #pragma unroll
      for (int ni = 0; ni < 4; ni++)
        acc[mi][ni] = __builtin_amdgcn_mfma_f32_16x16x32_f16(af[mi], bf[ni], acc[mi][ni], 0, 0, 0);
  }
  // epilogue: write m in fp16 (input to the h-GEMM)
  size_t rowbase = (size_t)b * SEQ;
  #pragma unroll
  for (int mi = 0; mi < 4; mi++) {
    #pragma unroll
    for (int ni = 0; ni < 4; ni++) {
      int kout = k0 + wc * 64 + ni * 16 + lm;
      #pragma unroll
      for (int r = 0; r < 4; r++) {
        int sout = s0 + wr * 64 + mi * 16 + q * 4 + r;
        mh[(rowbase + sout) * KMEM + kout] = (_Float16)acc[mi][ni][r];
      }
    }
  }
}

// ---------------- h = relu([m, x] . W_h^T + b); also h[:, -1, :] tail ----------------
// GEMM M=32768 N=1024 K=768, 128x128 tile. XCD-aware swizzle: XCD (id%8)
// processes complete mt rows (all 8 nt consecutively) so each A-tile is
// fetched into exactly one XCD's L2, once. Double-buffered staging.
__global__ __launch_bounds__(256) void h_kernel(
    const _Float16* __restrict__ mh, const _Float16* __restrict__ xh,
    const _Float16* __restrict__ Wh, const float* __restrict__ Whb,
    float* __restrict__ out)
{
  __shared__ _Float16 As[2][128 * 32];
  __shared__ _Float16 Bs[2][128 * 32];
  int id = blockIdx.y * 8 + blockIdx.x;   // dispatch-linear id (x fastest)
  int xcd = id & 7;
  int j = id >> 3;
  int mt = (j >> 3) * 8 + xcd;            // 0..255: mt-groups pinned per XCD
  int nt = j & 7;
  int tid = threadIdx.x, w = tid >> 6, lane = tid & 63;
  int wr = w >> 1, wc = w & 1, lm = lane & 15, q = lane >> 4;

  f32x4 acc[4][4] = {};
  // preload iter 0 into buf 0
  {
    #pragma unroll
    for (int p2 = 0; p2 < 2; p2++) {
      int c = p2 * 256 + tid;
      int row = c >> 2, ch = c & 3;
      size_t rg = (size_t)mt * 128 + row;
      load_lds16(mh + rg * KMEM + ch * 8, As[0] + (size_t)c * 8);
      load_lds16(Wh + (size_t)(nt * 128 + row) * KC + ch * 8, Bs[0] + (size_t)c * 8);
    }
  }
  for (int it = 0; it < 24; ++it) {
    int buf = it & 1;
    __syncthreads();
    if (it + 1 < 24) {
      int kk = (it + 1) * 32;
      #pragma unroll
      for (int p2 = 0; p2 < 2; p2++) {
        int c = p2 * 256 + tid;
        int row = c >> 2, ch = c & 3;
        size_t rg = (size_t)mt * 128 + row;
        const _Float16* srcA = (kk < KMEM)
            ? (mh + rg * KMEM + kk + ch * 8)
            : (xh + rg * DIN + (kk - KMEM) + ch * 8);
        load_lds16(srcA, As[buf ^ 1] + (size_t)c * 8);
        load_lds16(Wh + (size_t)(nt * 128 + row) * KC + kk + ch * 8,
                   Bs[buf ^ 1] + (size_t)c * 8);
      }
    }
    half8 af[4], bf[4];
    #pragma unroll
    for (int mi = 0; mi < 4; mi++)
      af[mi] = *((const half8*)(As[buf] + (wr * 64 + mi * 16 + lm) * 32 + q * 8));
    #pragma unroll
    for (int ni = 0; ni < 4; ni++)
      bf[ni] = *((const half8*)(Bs[buf] + (wc * 64 + ni * 16 + lm) * 32 + q * 8));
    #pragma unroll
    for (int mi = 0; mi < 4; mi++)
      #pragma unroll
      for (int ni = 0; ni < 4; ni++)
        acc[mi][ni] = __builtin_amdgcn_mfma_f32_16x16x32_f16(af[mi], bf[ni], acc[mi][ni], 0, 0, 0);
  }
  // epilogue: bias + relu + store fp32 (+ last-timestep tail)
  #pragma unroll
  for (int ni = 0; ni < 4; ni++) {
    int colg = nt * 128 + wc * 64 + ni * 16 + lm;
    float bias = Whb[colg];
    #pragma unroll
    for (int mi = 0; mi < 4; mi++) {
      #pragma unroll
      for (int r = 0; r < 4; r++) {
        int rowg = mt * 128 + wr * 64 + mi * 16 + q * 4 + r;
        float v = acc[mi][ni][r] + bias;
        v = v > 0.f ? v : 0.f;
        out[(size_t)rowg * HID + colg] = v;
        if ((rowg & (SEQ - 1)) == SEQ - 1)
          out[OUT_H_ELEMS + (size_t)(rowg >> 12) * HID + colg] = v;
      }
    }
  }
}

extern "C" void kernel_launch(void* const* d_in, const int* in_sizes, int n_in,
                              void* d_out, int out_size, void* d_ws, size_t ws_size,
                              hipStream_t stream) {
  const float* x   = (const float*)d_in[0];   // (8, 4096, 512)
  const float* Wu  = (const float*)d_in[1];   // (1, 512)
  const float* Wub = (const float*)d_in[2];   // (1,)
  const float* Whw = (const float*)d_in[3];   // (1024, 768)
  const float* Whb = (const float*)d_in[4];   // (1024,)
  const float* Hf  = (const float*)d_in[5];   // (256, 4096)
  float* out = (float*)d_out;

  char* ws = (char*)d_ws;
  _Float16* Hh = (_Float16*)(ws);                         // 2,097,152 B
  _Float16* Wh = (_Float16*)(ws + 2097152);               // 1,572,864 B
  _Float16* v2 = (_Float16*)(ws + 3670016);               //   557,056 B
  _Float16* xh = (_Float16*)(ws + 4227072);               // 33,554,432 B
  _Float16* mh = (_Float16*)(ws + 37781504);              // 16,777,216 B  (end 54,558,720)

  prep_kernel<<<dim3(1024), dim3(256), 0, stream>>>(Hf, Whw, Hh, Wh, v2);
  u_kernel<<<dim3(8192), dim3(256), 0, stream>>>(x, Wu, Wub, xh, v2);
  conv_kernel<<<dim3(16, 32), dim3(256), 0, stream>>>(Hh, v2, mh);
  h_kernel<<<dim3(8, 256), dim3(256), 0, stream>>>(mh, xh, Wh, Whb, out);
}

// Round 5
// 332.513 us; speedup vs baseline: 1.2552x; 1.0388x over previous
//
#include <hip/hip_runtime.h>

typedef _Float16 half8 __attribute__((ext_vector_type(8)));
typedef float f32x4 __attribute__((ext_vector_type(4)));

#define SEQ   4096
#define DIN   512
#define HID   1024
#define KMEM  256
#define NB    8
#define KC    768        // KMEM + DIN
#define VP    4352       // padded length of each phase copy of reversed u
#define OUT_H_ELEMS 33554432ull   // 8*4096*1024

__device__ __forceinline__ void load_lds16(const void* g, void* l) {
  __builtin_amdgcn_global_load_lds(
      (const __attribute__((address_space(1))) unsigned int*)g,
      (__attribute__((address_space(3))) unsigned int*)l, 16, 0, 0);
}

// ---------------- u = relu(x . W_u + b); emit xh (fp16) and v2 ----------------
// Fused prep: Hh/Wh casts and v2 pad-zero (only the 256 tail/head elems per
// phase that u's diagonal writes don't cover — no race with the u writes).
// v2[b][p][t] = (0 <= t-p < 4096) ? u[b, 4095 - (t-p)] : 0
__global__ __launch_bounds__(256) void u_kernel(
    const float* __restrict__ x, const float* __restrict__ Wu,
    const float* __restrict__ Wub,
    const float* __restrict__ Hf, const float* __restrict__ Wf,
    _Float16* __restrict__ xh, _Float16* __restrict__ v2,
    _Float16* __restrict__ Hh, _Float16* __restrict__ Wh)
{
  int tid_g = blockIdx.x * 256 + threadIdx.x;      // 0..2097151
  if (tid_g < KMEM * SEQ) Hh[tid_g] = (_Float16)Hf[tid_g];
  if (tid_g < HID * KC)   Wh[tid_g] = (_Float16)Wf[tid_g];
  if (tid_g < NB * 8 * 256) {                      // v2 pad zero
    int b2 = tid_g >> 11, rem = tid_g & 2047, p = rem >> 8, z = rem & 255;
    int t = (z < p) ? z : 4096 + z;                // [0,p) U [4096+p, 4352)
    v2[((size_t)b2 * 8 + p) * VP + t] = (_Float16)0.f;
  }

  int w = threadIdx.x >> 6, lane = threadIdx.x & 63;
  int row = blockIdx.x * 4 + w;               // 0..32767  (= b*4096 + s)
  const float4* xr = (const float4*)(x + (size_t)row * DIN);
  const float4* wr = (const float4*)Wu;
  float4 a0 = xr[lane * 2], a1 = xr[lane * 2 + 1];
  float4 w0 = wr[lane * 2], w1 = wr[lane * 2 + 1];
  float dot = a0.x * w0.x + a0.y * w0.y + a0.z * w0.z + a0.w * w0.w
            + a1.x * w1.x + a1.y * w1.y + a1.z * w1.z + a1.w * w1.w;
  half8 hv;
  hv[0] = (_Float16)a0.x; hv[1] = (_Float16)a0.y;
  hv[2] = (_Float16)a0.z; hv[3] = (_Float16)a0.w;
  hv[4] = (_Float16)a1.x; hv[5] = (_Float16)a1.y;
  hv[6] = (_Float16)a1.z; hv[7] = (_Float16)a1.w;
  *((half8*)(xh + (size_t)row * DIN + lane * 8)) = hv;
  #pragma unroll
  for (int off = 32; off > 0; off >>= 1) dot += __shfl_xor(dot, off);
  float u = dot + Wub[0];
  u = u > 0.f ? u : 0.f;
  if (lane < 8) {
    int s = row & (SEQ - 1), b = row >> 12;
    v2[(size_t)b * 8 * VP + (size_t)lane * VP + (4095 - s + lane)] = (_Float16)u;
  }
}

// ---------------- conv: m[b,s,k] = sum_{r=0..s} u[b,s-r] * H[k,r] ----------------
// 64-row s-tiles (grid 16x64 = 1024 blocks = 4 blocks/CU) for latency hiding.
// Wave tile 32x64 (2x4 MFMA). Double-buffered global_load_lds staging, one
// barrier per iter. A = 8-phase-replicated u-window (pad zeros = causal mask),
// loop-invariant LDS frag offsets.
__global__ __launch_bounds__(256) void conv_kernel(
    const _Float16* __restrict__ Hh, const _Float16* __restrict__ v2,
    _Float16* __restrict__ mh)
{
  __shared__ _Float16 Bs[2][128 * 32];  // [col][r-chunk], stride 32
  __shared__ _Float16 Aw[2][8 * 104];   // 8 phase copies of the u-window
  int cb = blockIdx.x;                  // 0..15
  int b = cb >> 1, kt = cb & 1;
  int by = blockIdx.y;                  // 0..63
  int its = (by & 1) ? (63 - (by >> 1)) : (by >> 1);  // interleave heavy/light
  int s0 = its * 64, k0 = kt * 128;
  int tid = threadIdx.x;
  int w = tid >> 6, lane = tid & 63;
  int wr = w >> 1, wc = w & 1;
  int lm = lane & 15, q = lane >> 4;
  const _Float16* v2b = v2 + (size_t)b * 8 * VP;
  int gbase0 = 4032 - s0;               // window start at r0=0 (8-aligned, >=0)

  // loop-invariant A-frag LDS offsets
  int aoffs[2];
  #pragma unroll
  for (int mi = 0; mi < 2; mi++) {
    int X = wr * 32 + mi * 16 + lm;     // s-offset within tile (0..63)
    int p = (X + 1) & 7;                // phase making the read 16B-aligned
    aoffs[mi] = p * 104 + (63 - X + p) + q * 8;
  }
  int boffs[4];
  #pragma unroll
  for (int ni = 0; ni < 4; ni++)
    boffs[ni] = (wc * 64 + ni * 16 + lm) * 32 + q * 8;

  int ap = tid / 13, aidx = tid - ap * 13;   // A staging map (104 x 16B chunks)

  f32x4 acc[2][4] = {};
  int iters = 2 * (its + 1);

  // preload iter 0 into buf 0
  {
    if (tid < 104)
      load_lds16(v2b + (size_t)ap * VP + gbase0 + aidx * 8, Aw[0] + tid * 8);
    #pragma unroll
    for (int p2 = 0; p2 < 2; p2++) {
      int c = p2 * 256 + tid;
      int col = c >> 2, ch = c & 3;
      load_lds16(Hh + (size_t)(k0 + col) * SEQ + ch * 8, Bs[0] + (size_t)c * 8);
    }
  }

  for (int it = 0; it < iters; ++it) {
    int buf = it & 1;
    __syncthreads();                    // vmcnt(0): buf's loads landed
    if (it + 1 < iters) {               // prefetch next chunk into buf^1
      int r0 = (it + 1) * 32;
      if (tid < 104)
        load_lds16(v2b + (size_t)ap * VP + gbase0 + r0 + aidx * 8, Aw[buf ^ 1] + tid * 8);
      #pragma unroll
      for (int p2 = 0; p2 < 2; p2++) {
        int c = p2 * 256 + tid;
        int col = c >> 2, ch = c & 3;
        load_lds16(Hh + (size_t)(k0 + col) * SEQ + r0 + ch * 8, Bs[buf ^ 1] + (size_t)c * 8);
      }
    }
    half8 af[2], bf[4];
    #pragma unroll
    for (int mi = 0; mi < 2; mi++) af[mi] = *((const half8*)(Aw[buf] + aoffs[mi]));
    #pragma unroll
    for (int ni = 0; ni < 4; ni++) bf[ni] = *((const half8*)(Bs[buf] + boffs[ni]));
    #pragma unroll
    for (int mi = 0; mi < 2; mi++)
      #pragma unroll
      for (int ni = 0; ni < 4; ni++)
        acc[mi][ni] = __builtin_amdgcn_mfma_f32_16x16x32_f16(af[mi], bf[ni], acc[mi][ni], 0, 0, 0);
  }
  // epilogue: write m in fp16 (input to the h-GEMM)
  size_t rowbase = (size_t)b * SEQ;
  #pragma unroll
  for (int mi = 0; mi < 2; mi++) {
    #pragma unroll
    for (int ni = 0; ni < 4; ni++) {
      int kout = k0 + wc * 64 + ni * 16 + lm;
      #pragma unroll
      for (int r = 0; r < 4; r++) {
        int sout = s0 + wr * 32 + mi * 16 + q * 4 + r;
        mh[(rowbase + sout) * KMEM + kout] = (_Float16)acc[mi][ni][r];
      }
    }
  }
}

// ---------------- h = relu([m, x] . W_h^T + b); also h[:, -1, :] tail ----------------
// GEMM M=32768 N=1024 K=768, 128x128 tile. XCD-aware swizzle: XCD (id%8)
// processes complete mt rows so each A-tile is fetched into exactly one
// XCD's L2, once. Double-buffered staging, one barrier per iter.
__global__ __launch_bounds__(256) void h_kernel(
    const _Float16* __restrict__ mh, const _Float16* __restrict__ xh,
    const _Float16* __restrict__ Wh, const float* __restrict__ Whb,
    float* __restrict__ out)
{
  __shared__ _Float16 As[2][128 * 32];
  __shared__ _Float16 Bs[2][128 * 32];
  int id = blockIdx.y * 8 + blockIdx.x;   // dispatch-linear id (x fastest)
  int xcd = id & 7;
  int j = id >> 3;
  int mt = (j >> 3) * 8 + xcd;            // 0..255: mt-groups pinned per XCD
  int nt = j & 7;
  int tid = threadIdx.x, w = tid >> 6, lane = tid & 63;
  int wr = w >> 1, wc = w & 1, lm = lane & 15, q = lane >> 4;

  f32x4 acc[4][4] = {};
  // preload iter 0 into buf 0
  {
    #pragma unroll
    for (int p2 = 0; p2 < 2; p2++) {
      int c = p2 * 256 + tid;
      int row = c >> 2, ch = c & 3;
      size_t rg = (size_t)mt * 128 + row;
      load_lds16(mh + rg * KMEM + ch * 8, As[0] + (size_t)c * 8);
      load_lds16(Wh + (size_t)(nt * 128 + row) * KC + ch * 8, Bs[0] + (size_t)c * 8);
    }
  }
  for (int it = 0; it < 24; ++it) {
    int buf = it & 1;
    __syncthreads();
    if (it + 1 < 24) {
      int kk = (it + 1) * 32;
      #pragma unroll
      for (int p2 = 0; p2 < 2; p2++) {
        int c = p2 * 256 + tid;
        int row = c >> 2, ch = c & 3;
        size_t rg = (size_t)mt * 128 + row;
        const _Float16* srcA = (kk < KMEM)
            ? (mh + rg * KMEM + kk + ch * 8)
            : (xh + rg * DIN + (kk - KMEM) + ch * 8);
        load_lds16(srcA, As[buf ^ 1] + (size_t)c * 8);
        load_lds16(Wh + (size_t)(nt * 128 + row) * KC + kk + ch * 8,
                   Bs[buf ^ 1] + (size_t)c * 8);
      }
    }
    half8 af[4], bf[4];
    #pragma unroll
    for (int mi = 0; mi < 4; mi++)
      af[mi] = *((const half8*)(As[buf] + (wr * 64 + mi * 16 + lm) * 32 + q * 8));
    #pragma unroll
    for (int ni = 0; ni < 4; ni++)
      bf[ni] = *((const half8*)(Bs[buf] + (wc * 64 + ni * 16 + lm) * 32 + q * 8));
    #pragma unroll
    for (int mi = 0; mi < 4; mi++)
      #pragma unroll
      for (int ni = 0; ni < 4; ni++)
        acc[mi][ni] = __builtin_amdgcn_mfma_f32_16x16x32_f16(af[mi], bf[ni], acc[mi][ni], 0, 0, 0);
  }
  // epilogue: bias + relu + store fp32 (+ last-timestep tail)
  #pragma unroll
  for (int ni = 0; ni < 4; ni++) {
    int colg = nt * 128 + wc * 64 + ni * 16 + lm;
    float bias = Whb[colg];
    #pragma unroll
    for (int mi = 0; mi < 4; mi++) {
      #pragma unroll
      for (int r = 0; r < 4; r++) {
        int rowg = mt * 128 + wr * 64 + mi * 16 + q * 4 + r;
        float v = acc[mi][ni][r] + bias;
        v = v > 0.f ? v : 0.f;
        out[(size_t)rowg * HID + colg] = v;
        if ((rowg & (SEQ - 1)) == SEQ - 1)
          out[OUT_H_ELEMS + (size_t)(rowg >> 12) * HID + colg] = v;
      }
    }
  }
}

extern "C" void kernel_launch(void* const* d_in, const int* in_sizes, int n_in,
                              void* d_out, int out_size, void* d_ws, size_t ws_size,
                              hipStream_t stream) {
  const float* x   = (const float*)d_in[0];   // (8, 4096, 512)
  const float* Wu  = (const float*)d_in[1];   // (1, 512)
  const float* Wub = (const float*)d_in[2];   // (1,)
  const float* Whw = (const float*)d_in[3];   // (1024, 768)
  const float* Whb = (const float*)d_in[4];   // (1024,)
  const float* Hf  = (const float*)d_in[5];   // (256, 4096)
  float* out = (float*)d_out;

  char* ws = (char*)d_ws;
  _Float16* Hh = (_Float16*)(ws);                         // 2,097,152 B
  _Float16* Wh = (_Float16*)(ws + 2097152);               // 1,572,864 B
  _Float16* v2 = (_Float16*)(ws + 3670016);               //   557,056 B
  _Float16* xh = (_Float16*)(ws + 4227072);               // 33,554,432 B
  _Float16* mh = (_Float16*)(ws + 37781504);              // 16,777,216 B  (end 54,558,720)

  u_kernel<<<dim3(8192), dim3(256), 0, stream>>>(x, Wu, Wub, Hf, Whw, xh, v2, Hh, Wh);
  conv_kernel<<<dim3(16, 64), dim3(256), 0, stream>>>(Hh, v2, mh);
  h_kernel<<<dim3(8, 256), dim3(256), 0, stream>>>(mh, xh, Wh, Whb, out);
}